// Round 10
// baseline (331.602 us; speedup 1.0000x reference)
//
#include <hip/hip_runtime.h>
#include <stdint.h>

// ---------------------------------------------------------------------------
// RandomizedBertSelfAttention: fused QKV projection + flash attention.
// R10 = R9 + (1) reduce_k fused into attn_k via last-block-combine (pair
// counter in ws, zeroed by stream memset between qkv and attn; partials +
// __threadfence + atomicAdd; second finisher reads partner partial and
// writes final out) and (2) XCD-aware linear grids: qkv groups 4 m-tiles
// (+ all W, ~4.3 MB) per XCD L2; attn groups 3 (h,sp) sets (~3 MB) per XCD.
// Attn math, qkv K-loop, and all LDS layouts unchanged from R9.
// ---------------------------------------------------------------------------

typedef float    f32x4 __attribute__((ext_vector_type(4)));
typedef _Float16 h16x8 __attribute__((ext_vector_type(8)));
typedef _Float16 h16x4 __attribute__((ext_vector_type(4)));
typedef _Float16 h16x2 __attribute__((ext_vector_type(2)));
typedef __fp16   fp16x2 __attribute__((ext_vector_type(2)));
typedef unsigned short u16;

#define MFMA32(A, B, C) __builtin_amdgcn_mfma_f32_16x16x32_f16((A), (B), (C), 0, 0, 0)
#define ZERO4 ((f32x4){0.f, 0.f, 0.f, 0.f})

#define SEQ 4096
#define HID 768
#define NH  12
#define DH  64

#define CEXP 0.18033688011112042f   // log2(e)/sqrt(64), folded into Q

__device__ __forceinline__ u16 f2h(float f) {
  union { _Float16 h; u16 u; } v;
  v.h = (_Float16)f;
  return v.u;
}
__device__ __forceinline__ float h2f(u16 u) {
  union { u16 u; _Float16 h; } v;
  v.u = u;
  return (float)v.h;
}

__device__ __forceinline__ void gload_lds16(const void* g, void* l) {
  __builtin_amdgcn_global_load_lds(
      (__attribute__((address_space(1))) void*)(g),
      (__attribute__((address_space(3))) void*)(l),
      16, 0, 0);
}

// ---------------------------------------------------------------------------
// Kernel 1: cast x, Wq, Wk, Wv to fp16
// ---------------------------------------------------------------------------
__global__ __launch_bounds__(256) void cast_all_k(
    const float* __restrict__ x,  const float* __restrict__ wq,
    const float* __restrict__ wk, const float* __restrict__ wv,
    u16* __restrict__ xh,  u16* __restrict__ wqh,
    u16* __restrict__ wkh, u16* __restrict__ wvh)
{
  int i = blockIdx.x * 256 + threadIdx.x;
  const int NX4 = (SEQ * HID) / 4;
  const int NW4 = (HID * HID) / 4;
  const float4* src; ushort4* dst; int idx;
  if (i < NX4) {
    src = (const float4*)x; dst = (ushort4*)xh; idx = i;
  } else {
    int j = i - NX4;
    int w = j / NW4;
    idx = j - w * NW4;
    src = (const float4*)(w == 0 ? wq : (w == 1 ? wk : wv));
    dst = (ushort4*)(w == 0 ? wqh : (w == 1 ? wkh : wvh));
  }
  float4 v = src[idx];
  ushort4 o;
  o.x = f2h(v.x); o.y = f2h(v.y); o.z = f2h(v.z); o.w = f2h(v.w);
  dst[idx] = o;
}

// ---------------------------------------------------------------------------
// Kernel 2: QKV projection GEMM, C = x @ W^T + b. 128x128 tile, BK=64,
// XOR-swizzled LDS staging, coalesced LDS-transpose epilogue (R9).
// Grid: 576 linear, XCD-grouped: bid&7 = XCD, 4 m-tiles + all 18 (x,z)
// combos per XCD -> per-XCD L2 working set ~4.3 MB (A 786KB + W 3.5MB).
// z==0 (Q): pre-scaled by CEXP. z==2 (V): Vt[hid][s] with pi per 32-kv group.
// ---------------------------------------------------------------------------
__global__ __launch_bounds__(256, 3) void qkv_gemm_k(
    const u16* __restrict__ xh,
    const u16* __restrict__ wqh, const u16* __restrict__ wkh, const u16* __restrict__ wvh,
    const float* __restrict__ bq, const float* __restrict__ bk, const float* __restrict__ bv,
    u16* __restrict__ Qh, u16* __restrict__ Kh, u16* __restrict__ Vt)
{
  __shared__ u16 S[128 * 128];   // 32 KB: K-loop A/B; epilogue transpose tile

  const int t = threadIdx.x;
  const int wave = t >> 6, lane = t & 63;
  const int m = lane & 15, quad = lane >> 4;

  // XCD-aware decode: blocks with bid%8==c land on XCD c (dispatch heuristic)
  const int bid = blockIdx.x;
  const int xcd = bid & 7;
  const int kk  = bid >> 3;            // 0..71
  const int yt  = xcd * 4 + (kk / 18); // m-tile 0..31 (4 per XCD)
  const int jj  = kk % 18;
  const int xt  = jj % 6;              // n-tile (z varies slowest: W-locality)
  const int z   = jj / 6;
  const int n0 = xt * 128;
  const int m0 = yt * 128;

  const u16*   W    = (z == 0) ? wqh : (z == 1) ? wkh : wvh;
  const float* bias = (z == 0) ? bq  : (z == 1) ? bk  : bv;

  const int wm = (wave >> 1) * 64;
  const int wn = (wave & 1) * 64;

  f32x4 acc[4][4];
#pragma unroll
  for (int i = 0; i < 4; i++)
#pragma unroll
    for (int j = 0; j < 4; j++) acc[i][j] = ZERO4;

  const int srow = wave * 8 + (lane >> 3);
  const int scg  = (lane & 7) ^ (srow & 7);
  const u16* gA = xh + (m0 + srow) * HID + scg * 8;
  const u16* gB = W  + (n0 + srow) * HID + scg * 8;
  u16* lA = S + wave * 512;
  u16* lB = S + 8192 + wave * 512;

  for (int k0 = 0; k0 < HID; k0 += 64) {
    __syncthreads();
#pragma unroll
    for (int c = 0; c < 4; c++) {
      gload_lds16(gA + c * 32 * HID + k0, lA + c * 2048);
      gload_lds16(gB + c * 32 * HID + k0, lB + c * 2048);
    }
    __syncthreads();

#pragma unroll
    for (int s = 0; s < 2; s++) {
      h16x8 af[4], bf[4];
#pragma unroll
      for (int i = 0; i < 4; i++)
        af[i] = *(const h16x8*)(S + (wm + i * 16 + m) * 64
                                + ((s * 4 + quad) ^ (m & 7)) * 8);
#pragma unroll
      for (int j = 0; j < 4; j++)
        bf[j] = *(const h16x8*)(S + 8192 + (wn + j * 16 + m) * 64
                                + ((s * 4 + quad) ^ (m & 7)) * 8);
#pragma unroll
      for (int i = 0; i < 4; i++)
#pragma unroll
        for (int j = 0; j < 4; j++)
          acc[i][j] = MFMA32(af[i], bf[j], acc[i][j]);
    }
  }

  __syncthreads();   // all frag reads done — S becomes the epilogue tile

  if (z < 2) {
    const float sc = (z == 0) ? CEXP : 1.0f;
#pragma unroll
    for (int i = 0; i < 4; i++) {
      int sl = wm + i * 16 + quad * 4;
#pragma unroll
      for (int j = 0; j < 4; j++) {
        int colp = wn + j * 16 + m;
        float bb = bias[n0 + colp];
        int c = colp >> 3, sub = colp & 7;
#pragma unroll
        for (int r = 0; r < 4; r++)
          S[(sl + r) * 128 + ((c ^ ((sl + r) & 15)) * 8) + sub] =
              f2h((acc[i][j][r] + bb) * sc);
      }
    }
    __syncthreads();
    u16* outp = (z == 0) ? Qh : Kh;
    const int ch = t & 15;
#pragma unroll
    for (int rr = 0; rr < 8; rr++) {
      int s = rr * 16 + (t >> 4);
      h16x8 v = *(const h16x8*)(S + s * 128 + ((ch ^ (s & 15)) * 8));
      *(h16x8*)(outp + (m0 + s) * HID + n0 + ch * 8) = v;
    }
  } else {
#pragma unroll
    for (int i = 0; i < 4; i++) {
      int sl = wm + i * 16 + quad * 4;
      int vp = (sl & ~31) + ((sl >> 2) & 3) * 8 + ((sl >> 4) & 1) * 4;
#pragma unroll
      for (int j = 0; j < 4; j++) {
        int nl = wn + j * 16 + m;
        float bb = bias[n0 + nl];
        h16x4 o;
        o[0] = (_Float16)(acc[i][j][0] + bb);
        o[1] = (_Float16)(acc[i][j][1] + bb);
        o[2] = (_Float16)(acc[i][j][2] + bb);
        o[3] = (_Float16)(acc[i][j][3] + bb);
        *(h16x4*)(S + nl * 128 + (((vp >> 3) ^ (nl & 15)) * 8) + (vp & 7)) = o;
      }
    }
    __syncthreads();
    const int ch = t & 15;
#pragma unroll
    for (int rr = 0; rr < 8; rr++) {
      int n = rr * 16 + (t >> 4);
      h16x8 v = *(const h16x8*)(S + n * 128 + ((ch ^ (n & 15)) * 8));
      *(h16x8*)(Vt + (n0 + n) * SEQ + m0 + ch * 8) = v;
    }
  }
}

// ---------------------------------------------------------------------------
// Kernel 3: flash attention, split-KV x2, WITH fused combine (replaces
// reduce_k). Grid 768 linear, XCD-grouped: 3 (h,sp) sets per XCD (~3 MB K/V).
// Both pair-blocks write partials (sp=0 -> out0 fp32, sp=1 -> Op1 fp16) + L,
// __threadfence, atomicAdd(cnt[pair]); the second finisher reads the partner
// partial + L and writes the final normalized out. Combiner passes its own
// partial through fp16 when sp==1 so numerics match the old reduce exactly.
// ---------------------------------------------------------------------------
__global__ __launch_bounds__(256, 3) void attn_k(
    const u16* __restrict__ Qh, const u16* __restrict__ Kh, const u16* __restrict__ Vt,
    float* __restrict__ out0, u16* __restrict__ Op1, float* __restrict__ Lp,
    int* __restrict__ cnt)
{
  __shared__ u16 Ks[128 * 64];    // 16 KB [kv][d], chunks swizzled ^(kv&7)
  __shared__ u16 Vs[64 * 128];    // 16 KB [d][kv'], pi-permuted, swizzled ^(d&15)
  __shared__ int role;

  const int t = threadIdx.x;
  const int wave = t >> 6, lane = t & 63;
  const int m = lane & 15, quad = lane >> 4;

  // XCD-aware decode: hs = (h,sp) group, 3 per XCD; x = q-tile
  const int bid = blockIdx.x;
  const int xcd = bid & 7;
  const int kk  = bid >> 3;            // 0..95
  const int hs  = xcd * 3 + (kk >> 5); // 0..23
  const int x   = kk & 31;
  const int h   = hs % NH;
  const int sp  = hs / NH;
  const int q0 = x * 128;
  const int kvbase = sp * 2048;
  const int pair = x * NH + h;

  h16x8 qf[2][2];
#pragma unroll
  for (int qn = 0; qn < 2; qn++)
#pragma unroll
    for (int ks = 0; ks < 2; ks++)
      qf[qn][ks] = *(const h16x8*)(Qh + (q0 + wave * 32 + qn * 16 + m) * HID
                                   + h * DH + ks * 32 + quad * 8);

  f32x4 O[2][4];
#pragma unroll
  for (int qn = 0; qn < 2; qn++)
#pragma unroll
    for (int jd = 0; jd < 4; jd++) O[qn][jd] = ZERO4;
  float lsum[2] = {0.f, 0.f};

  const int krow_b = wave * 8 + (lane >> 3);
  const int kcl    = lane & 7;
  const int vrow_b = wave * 4 + (lane >> 4);
  const int vcl    = lane & 15;

  for (int it = 0; it < 16; ++it) {
    const int kv0 = kvbase + it * 128;
    __syncthreads();
#pragma unroll
    for (int c = 0; c < 4; c++) {
      int row = c * 32 + krow_b;
      int cg  = kcl ^ (row & 7);
      gload_lds16(Kh + (kv0 + row) * HID + h * DH + cg * 8,
                  Ks + c * 2048 + wave * 512);
      int d  = c * 16 + vrow_b;
      int vg = vcl ^ (d & 15);
      gload_lds16(Vt + (h * DH + d) * SEQ + kv0 + vg * 8,
                  Vs + c * 2048 + wave * 512);
    }
    __syncthreads();

#pragma unroll
    for (int p = 0; p < 4; ++p) {
      const int krow0 = (2 * p) * 16 + m;
      const int krow1 = krow0 + 16;
      h16x8 kb00 = *(const h16x8*)(Ks + krow0 * 64 + ((    quad) ^ (m & 7)) * 8);
      h16x8 kb01 = *(const h16x8*)(Ks + krow0 * 64 + ((4 + quad) ^ (m & 7)) * 8);
      h16x8 kb10 = *(const h16x8*)(Ks + krow1 * 64 + ((    quad) ^ (m & 7)) * 8);
      h16x8 kb11 = *(const h16x8*)(Ks + krow1 * 64 + ((4 + quad) ^ (m & 7)) * 8);

      h16x8 vb[4];
#pragma unroll
      for (int jd = 0; jd < 4; jd++) {
        int d = jd * 16 + m;
        vb[jd] = *(const h16x8*)(Vs + d * 128 + (((p * 4 + quad) ^ m) * 8));
      }

#pragma unroll
      for (int qn = 0; qn < 2; qn++) {
        f32x4 S0 = MFMA32(kb00, qf[qn][0], ZERO4);
        S0       = MFMA32(kb01, qf[qn][1], S0);
        f32x4 S1 = MFMA32(kb10, qf[qn][0], ZERO4);
        S1       = MFMA32(kb11, qf[qn][1], S1);

        float e0 = __builtin_amdgcn_exp2f(S0[0]);
        float e1 = __builtin_amdgcn_exp2f(S0[1]);
        float e2 = __builtin_amdgcn_exp2f(S0[2]);
        float e3 = __builtin_amdgcn_exp2f(S0[3]);
        float e4 = __builtin_amdgcn_exp2f(S1[0]);
        float e5 = __builtin_amdgcn_exp2f(S1[1]);
        float e6 = __builtin_amdgcn_exp2f(S1[2]);
        float e7 = __builtin_amdgcn_exp2f(S1[3]);
        lsum[qn] += ((e0 + e1) + (e2 + e3)) + ((e4 + e5) + (e6 + e7));

        fp16x2 p01 = __builtin_amdgcn_cvt_pkrtz(e0, e1);
        fp16x2 p23 = __builtin_amdgcn_cvt_pkrtz(e2, e3);
        fp16x2 p45 = __builtin_amdgcn_cvt_pkrtz(e4, e5);
        fp16x2 p67 = __builtin_amdgcn_cvt_pkrtz(e6, e7);
        h16x2 q01 = __builtin_bit_cast(h16x2, p01);
        h16x2 q23 = __builtin_bit_cast(h16x2, p23);
        h16x2 q45 = __builtin_bit_cast(h16x2, p45);
        h16x2 q67 = __builtin_bit_cast(h16x2, p67);
        h16x4 pl = __builtin_shufflevector(q01, q23, 0, 1, 2, 3);
        h16x4 ph = __builtin_shufflevector(q45, q67, 0, 1, 2, 3);
        h16x8 pa = __builtin_shufflevector(pl, ph, 0, 1, 2, 3, 4, 5, 6, 7);

#pragma unroll
        for (int jd = 0; jd < 4; jd++)
          O[qn][jd] = MFMA32(pa, vb[jd], O[qn][jd]);
      }
    }
  }

  // ---- epilogue: L + partial write, then last-block combine ----
  float Lq[2];
#pragma unroll
  for (int qn = 0; qn < 2; qn++) {
    float v = lsum[qn];
    v += __shfl_xor(v, 16, 64);
    v += __shfl_xor(v, 32, 64);                // all lanes: full row sum
    Lq[qn] = v;
    if (quad == 0)
      Lp[sp * NH * SEQ + h * SEQ + q0 + wave * 32 + qn * 16 + m] = v;
  }
#pragma unroll
  for (int qn = 0; qn < 2; qn++)
#pragma unroll
    for (int jd = 0; jd < 4; jd++) {
      int col = h * DH + jd * 16 + m;
#pragma unroll
      for (int r = 0; r < 4; r++) {
        int row = q0 + wave * 32 + qn * 16 + quad * 4 + r;
        if (sp == 0) out0[row * HID + col] = O[qn][jd][r];
        else         Op1[row * HID + col] = f2h(O[qn][jd][r]);
      }
    }

  __threadfence();                             // release partial + L
  if (t == 0) role = atomicAdd(&cnt[pair], 1);
  __syncthreads();
  if (role == 0) return;                       // first finisher: partial only
  __threadfence();                             // acquire partner's writes

  float Lo[2];
#pragma unroll
  for (int qn = 0; qn < 2; qn++)
    Lo[qn] = Lp[(1 - sp) * NH * SEQ + h * SEQ + q0 + wave * 32 + qn * 16 + m];

#pragma unroll
  for (int qn = 0; qn < 2; qn++) {
    float invr[4];
#pragma unroll
    for (int r = 0; r < 4; r++) {
      float Ls = __shfl(Lq[qn], quad * 4 + r, 64);
      float Lr = __shfl(Lo[qn], quad * 4 + r, 64);
      invr[r] = __builtin_amdgcn_rcpf(Ls + Lr);
    }
#pragma unroll
    for (int jd = 0; jd < 4; jd++) {
      int col = h * DH + jd * 16 + m;
#pragma unroll
      for (int r = 0; r < 4; r++) {
        int row = q0 + wave * 32 + qn * 16 + quad * 4 + r;
        // match old reduce numerics: sp=1 partial always rounds through fp16
        float own = (sp == 1) ? h2f(f2h(O[qn][jd][r])) : O[qn][jd][r];
        float oth = (sp == 0) ? h2f(Op1[row * HID + col])
                              : out0[row * HID + col];
        out0[row * HID + col] = (own + oth) * invr[r];
      }
    }
  }
}

// ---------------------------------------------------------------------------
// Launch. ws layout (bytes) — TOTAL 28,704,768 (R0-proven footprint):
//   Qh [0, 6291456) | Kh [6291456, 12582912) | Vt [12582912, 18874368)
//   xh [18874368, 25165824) | wqh [25165824, 26345472) | wkh | wvh
//   Op1 (u16) aliases xh; Lp (f32, 393216 B) aliases wqh head;
//   cnt (int[384], 1536 B) at +25559040 (right after Lp, still in dead wqh),
//   zeroed by a stream-ordered hipMemsetAsync between qkv and attn.
// ---------------------------------------------------------------------------
extern "C" void kernel_launch(void* const* d_in, const int* in_sizes, int n_in,
                              void* d_out, int out_size, void* d_ws, size_t ws_size,
                              hipStream_t stream) {
  const float* x  = (const float*)d_in[0];
  const float* Wq = (const float*)d_in[1];
  const float* bq = (const float*)d_in[2];
  const float* Wk = (const float*)d_in[3];
  const float* bk = (const float*)d_in[4];
  const float* Wv = (const float*)d_in[5];
  const float* bv = (const float*)d_in[6];
  float* out = (float*)d_out;

  char* ws = (char*)d_ws;
  u16* Qh  = (u16*)(ws);
  u16* Kh  = (u16*)(ws + 6291456);
  u16* Vt  = (u16*)(ws + 12582912);
  u16* xh  = (u16*)(ws + 18874368);
  u16* wqh = (u16*)(ws + 25165824);
  u16* wkh = (u16*)(ws + 26345472);
  u16* wvh = (u16*)(ws + 27525120);
  u16*   Op1 = (u16*)(ws + 18874368);    // aliases xh (dead after qkv)
  float* Lp  = (float*)(ws + 25165824);  // aliases wqh (dead after qkv)
  int*   cnt = (int*)(ws + 25559040);    // after Lp, still in dead wqh

  cast_all_k<<<4800, 256, 0, stream>>>(x, Wq, Wk, Wv, xh, wqh, wkh, wvh);
  qkv_gemm_k<<<576, 256, 0, stream>>>(xh, wqh, wkh, wvh,
                                      bq, bk, bv, Qh, Kh, Vt);
  hipMemsetAsync(cnt, 0, 384 * sizeof(int), stream);  // pair counters = 0
  attn_k<<<768, 256, 0, stream>>>(Qh, Kh, Vt, out, Op1, Lp, cnt);
}

// Round 11
// 163.058 us; speedup vs baseline: 2.0336x; 2.0336x over previous
//
#include <hip/hip_runtime.h>
#include <stdint.h>

// ---------------------------------------------------------------------------
// RandomizedBertSelfAttention: fused QKV projection + flash attention.
// R11 = R9 (four kernels, separate reduce, NO fences/atomics) + R10's
// XCD-aware linear grids (the half of R10 the counters validated: FETCH
// 52->15.6 MB). R10's fused combine is reverted: its __threadfence() pair
// compiles to buffer_wbl2/buffer_inv on gfx950's non-coherent per-XCD L2 —
// each of 768 blocks flushed the whole 4 MB L2, destroying all locality
// (attn 63->238 us, MfmaUtil 8.7%). Lesson: no device-scope fences in hot
// kernels on this chip.
// ---------------------------------------------------------------------------

typedef float    f32x4 __attribute__((ext_vector_type(4)));
typedef _Float16 h16x8 __attribute__((ext_vector_type(8)));
typedef _Float16 h16x4 __attribute__((ext_vector_type(4)));
typedef _Float16 h16x2 __attribute__((ext_vector_type(2)));
typedef __fp16   fp16x2 __attribute__((ext_vector_type(2)));
typedef unsigned short u16;

#define MFMA32(A, B, C) __builtin_amdgcn_mfma_f32_16x16x32_f16((A), (B), (C), 0, 0, 0)
#define ZERO4 ((f32x4){0.f, 0.f, 0.f, 0.f})

#define SEQ 4096
#define HID 768
#define NH  12
#define DH  64

#define CEXP 0.18033688011112042f   // log2(e)/sqrt(64), folded into Q

__device__ __forceinline__ u16 f2h(float f) {
  union { _Float16 h; u16 u; } v;
  v.h = (_Float16)f;
  return v.u;
}
__device__ __forceinline__ float h2f(u16 u) {
  union { u16 u; _Float16 h; } v;
  v.u = u;
  return (float)v.h;
}

__device__ __forceinline__ void gload_lds16(const void* g, void* l) {
  __builtin_amdgcn_global_load_lds(
      (__attribute__((address_space(1))) void*)(g),
      (__attribute__((address_space(3))) void*)(l),
      16, 0, 0);
}

// ---------------------------------------------------------------------------
// Kernel 1: cast x, Wq, Wk, Wv to fp16
// ---------------------------------------------------------------------------
__global__ __launch_bounds__(256) void cast_all_k(
    const float* __restrict__ x,  const float* __restrict__ wq,
    const float* __restrict__ wk, const float* __restrict__ wv,
    u16* __restrict__ xh,  u16* __restrict__ wqh,
    u16* __restrict__ wkh, u16* __restrict__ wvh)
{
  int i = blockIdx.x * 256 + threadIdx.x;
  const int NX4 = (SEQ * HID) / 4;
  const int NW4 = (HID * HID) / 4;
  const float4* src; ushort4* dst; int idx;
  if (i < NX4) {
    src = (const float4*)x; dst = (ushort4*)xh; idx = i;
  } else {
    int j = i - NX4;
    int w = j / NW4;
    idx = j - w * NW4;
    src = (const float4*)(w == 0 ? wq : (w == 1 ? wk : wv));
    dst = (ushort4*)(w == 0 ? wqh : (w == 1 ? wkh : wvh));
  }
  float4 v = src[idx];
  ushort4 o;
  o.x = f2h(v.x); o.y = f2h(v.y); o.z = f2h(v.z); o.w = f2h(v.w);
  dst[idx] = o;
}

// ---------------------------------------------------------------------------
// Kernel 2: QKV projection GEMM, C = x @ W^T + b. 128x128 tile, BK=64,
// XOR-swizzled LDS staging, coalesced LDS-transpose epilogue (R9).
// Grid 576 linear, XCD-grouped (bid&7 = XCD): 4 m-tiles + all W per XCD
// (~4.3 MB working set per L2). Counters (R10): FETCH 52 -> 15.6 MB.
// z==0 (Q): pre-scaled by CEXP. z==2 (V): Vt[hid][s] with pi per 32-kv group.
// ---------------------------------------------------------------------------
__global__ __launch_bounds__(256, 3) void qkv_gemm_k(
    const u16* __restrict__ xh,
    const u16* __restrict__ wqh, const u16* __restrict__ wkh, const u16* __restrict__ wvh,
    const float* __restrict__ bq, const float* __restrict__ bk, const float* __restrict__ bv,
    u16* __restrict__ Qh, u16* __restrict__ Kh, u16* __restrict__ Vt)
{
  __shared__ u16 S[128 * 128];   // 32 KB: K-loop A/B; epilogue transpose tile

  const int t = threadIdx.x;
  const int wave = t >> 6, lane = t & 63;
  const int m = lane & 15, quad = lane >> 4;

  // XCD-aware decode (R10-proven bijection)
  const int bid = blockIdx.x;
  const int xcd = bid & 7;
  const int kk  = bid >> 3;            // 0..71
  const int yt  = xcd * 4 + (kk / 18); // m-tile 0..31 (4 per XCD)
  const int jj  = kk % 18;
  const int xt  = jj % 6;              // n-tile
  const int z   = jj / 6;
  const int n0 = xt * 128;
  const int m0 = yt * 128;

  const u16*   W    = (z == 0) ? wqh : (z == 1) ? wkh : wvh;
  const float* bias = (z == 0) ? bq  : (z == 1) ? bk  : bv;

  const int wm = (wave >> 1) * 64;
  const int wn = (wave & 1) * 64;

  f32x4 acc[4][4];
#pragma unroll
  for (int i = 0; i < 4; i++)
#pragma unroll
    for (int j = 0; j < 4; j++) acc[i][j] = ZERO4;

  const int srow = wave * 8 + (lane >> 3);
  const int scg  = (lane & 7) ^ (srow & 7);
  const u16* gA = xh + (m0 + srow) * HID + scg * 8;
  const u16* gB = W  + (n0 + srow) * HID + scg * 8;
  u16* lA = S + wave * 512;
  u16* lB = S + 8192 + wave * 512;

  for (int k0 = 0; k0 < HID; k0 += 64) {
    __syncthreads();
#pragma unroll
    for (int c = 0; c < 4; c++) {
      gload_lds16(gA + c * 32 * HID + k0, lA + c * 2048);
      gload_lds16(gB + c * 32 * HID + k0, lB + c * 2048);
    }
    __syncthreads();

#pragma unroll
    for (int s = 0; s < 2; s++) {
      h16x8 af[4], bf[4];
#pragma unroll
      for (int i = 0; i < 4; i++)
        af[i] = *(const h16x8*)(S + (wm + i * 16 + m) * 64
                                + ((s * 4 + quad) ^ (m & 7)) * 8);
#pragma unroll
      for (int j = 0; j < 4; j++)
        bf[j] = *(const h16x8*)(S + 8192 + (wn + j * 16 + m) * 64
                                + ((s * 4 + quad) ^ (m & 7)) * 8);
#pragma unroll
      for (int i = 0; i < 4; i++)
#pragma unroll
        for (int j = 0; j < 4; j++)
          acc[i][j] = MFMA32(af[i], bf[j], acc[i][j]);
    }
  }

  __syncthreads();   // all frag reads done — S becomes the epilogue tile

  if (z < 2) {
    const float sc = (z == 0) ? CEXP : 1.0f;
#pragma unroll
    for (int i = 0; i < 4; i++) {
      int sl = wm + i * 16 + quad * 4;
#pragma unroll
      for (int j = 0; j < 4; j++) {
        int colp = wn + j * 16 + m;
        float bb = bias[n0 + colp];
        int c = colp >> 3, sub = colp & 7;
#pragma unroll
        for (int r = 0; r < 4; r++)
          S[(sl + r) * 128 + ((c ^ ((sl + r) & 15)) * 8) + sub] =
              f2h((acc[i][j][r] + bb) * sc);
      }
    }
    __syncthreads();
    u16* outp = (z == 0) ? Qh : Kh;
    const int ch = t & 15;
#pragma unroll
    for (int rr = 0; rr < 8; rr++) {
      int s = rr * 16 + (t >> 4);
      h16x8 v = *(const h16x8*)(S + s * 128 + ((ch ^ (s & 15)) * 8));
      *(h16x8*)(outp + (m0 + s) * HID + n0 + ch * 8) = v;
    }
  } else {
#pragma unroll
    for (int i = 0; i < 4; i++) {
      int sl = wm + i * 16 + quad * 4;
      int vp = (sl & ~31) + ((sl >> 2) & 3) * 8 + ((sl >> 4) & 1) * 4;
#pragma unroll
      for (int j = 0; j < 4; j++) {
        int nl = wn + j * 16 + m;
        float bb = bias[n0 + nl];
        h16x4 o;
        o[0] = (_Float16)(acc[i][j][0] + bb);
        o[1] = (_Float16)(acc[i][j][1] + bb);
        o[2] = (_Float16)(acc[i][j][2] + bb);
        o[3] = (_Float16)(acc[i][j][3] + bb);
        *(h16x4*)(S + nl * 128 + (((vp >> 3) ^ (nl & 15)) * 8) + (vp & 7)) = o;
      }
    }
    __syncthreads();
    const int ch = t & 15;
#pragma unroll
    for (int rr = 0; rr < 8; rr++) {
      int n = rr * 16 + (t >> 4);
      h16x8 v = *(const h16x8*)(S + n * 128 + ((ch ^ (n & 15)) * 8));
      *(h16x8*)(Vt + (n0 + n) * SEQ + m0 + ch * 8) = v;
    }
  }
}

// ---------------------------------------------------------------------------
// Kernel 3: flash attention, split-KV x2 (R9 math, no fences/atomics).
// Grid 768 linear, XCD-grouped: 3 (h,sp) sets per XCD (~3 MB K/V per L2).
// Partials: sp=0 -> out0 fp32, sp=1 -> Op1 fp16; combined by reduce_k.
// ---------------------------------------------------------------------------
__global__ __launch_bounds__(256, 3) void attn_k(
    const u16* __restrict__ Qh, const u16* __restrict__ Kh, const u16* __restrict__ Vt,
    float* __restrict__ out0, u16* __restrict__ Op1, float* __restrict__ Lp)
{
  __shared__ u16 Ks[128 * 64];    // 16 KB [kv][d], chunks swizzled ^(kv&7)
  __shared__ u16 Vs[64 * 128];    // 16 KB [d][kv'], pi-permuted, swizzled ^(d&15)

  const int t = threadIdx.x;
  const int wave = t >> 6, lane = t & 63;
  const int m = lane & 15, quad = lane >> 4;

  // XCD-aware decode (R10-proven bijection)
  const int bid = blockIdx.x;
  const int xcd = bid & 7;
  const int kk  = bid >> 3;            // 0..95
  const int hs  = xcd * 3 + (kk >> 5); // 0..23
  const int x   = kk & 31;
  const int h   = hs % NH;
  const int sp  = hs / NH;
  const int q0 = x * 128;
  const int kvbase = sp * 2048;

  h16x8 qf[2][2];
#pragma unroll
  for (int qn = 0; qn < 2; qn++)
#pragma unroll
    for (int ks = 0; ks < 2; ks++)
      qf[qn][ks] = *(const h16x8*)(Qh + (q0 + wave * 32 + qn * 16 + m) * HID
                                   + h * DH + ks * 32 + quad * 8);

  f32x4 O[2][4];
#pragma unroll
  for (int qn = 0; qn < 2; qn++)
#pragma unroll
    for (int jd = 0; jd < 4; jd++) O[qn][jd] = ZERO4;
  float lsum[2] = {0.f, 0.f};

  const int krow_b = wave * 8 + (lane >> 3);
  const int kcl    = lane & 7;
  const int vrow_b = wave * 4 + (lane >> 4);
  const int vcl    = lane & 15;

  for (int it = 0; it < 16; ++it) {
    const int kv0 = kvbase + it * 128;
    __syncthreads();
#pragma unroll
    for (int c = 0; c < 4; c++) {
      int row = c * 32 + krow_b;
      int cg  = kcl ^ (row & 7);
      gload_lds16(Kh + (kv0 + row) * HID + h * DH + cg * 8,
                  Ks + c * 2048 + wave * 512);
      int d  = c * 16 + vrow_b;
      int vg = vcl ^ (d & 15);
      gload_lds16(Vt + (h * DH + d) * SEQ + kv0 + vg * 8,
                  Vs + c * 2048 + wave * 512);
    }
    __syncthreads();

#pragma unroll
    for (int p = 0; p < 4; ++p) {
      const int krow0 = (2 * p) * 16 + m;
      const int krow1 = krow0 + 16;
      h16x8 kb00 = *(const h16x8*)(Ks + krow0 * 64 + ((    quad) ^ (m & 7)) * 8);
      h16x8 kb01 = *(const h16x8*)(Ks + krow0 * 64 + ((4 + quad) ^ (m & 7)) * 8);
      h16x8 kb10 = *(const h16x8*)(Ks + krow1 * 64 + ((    quad) ^ (m & 7)) * 8);
      h16x8 kb11 = *(const h16x8*)(Ks + krow1 * 64 + ((4 + quad) ^ (m & 7)) * 8);

      h16x8 vb[4];
#pragma unroll
      for (int jd = 0; jd < 4; jd++) {
        int d = jd * 16 + m;
        vb[jd] = *(const h16x8*)(Vs + d * 128 + (((p * 4 + quad) ^ m) * 8));
      }

#pragma unroll
      for (int qn = 0; qn < 2; qn++) {
        f32x4 S0 = MFMA32(kb00, qf[qn][0], ZERO4);
        S0       = MFMA32(kb01, qf[qn][1], S0);
        f32x4 S1 = MFMA32(kb10, qf[qn][0], ZERO4);
        S1       = MFMA32(kb11, qf[qn][1], S1);

        float e0 = __builtin_amdgcn_exp2f(S0[0]);
        float e1 = __builtin_amdgcn_exp2f(S0[1]);
        float e2 = __builtin_amdgcn_exp2f(S0[2]);
        float e3 = __builtin_amdgcn_exp2f(S0[3]);
        float e4 = __builtin_amdgcn_exp2f(S1[0]);
        float e5 = __builtin_amdgcn_exp2f(S1[1]);
        float e6 = __builtin_amdgcn_exp2f(S1[2]);
        float e7 = __builtin_amdgcn_exp2f(S1[3]);
        lsum[qn] += ((e0 + e1) + (e2 + e3)) + ((e4 + e5) + (e6 + e7));

        fp16x2 p01 = __builtin_amdgcn_cvt_pkrtz(e0, e1);
        fp16x2 p23 = __builtin_amdgcn_cvt_pkrtz(e2, e3);
        fp16x2 p45 = __builtin_amdgcn_cvt_pkrtz(e4, e5);
        fp16x2 p67 = __builtin_amdgcn_cvt_pkrtz(e6, e7);
        h16x2 q01 = __builtin_bit_cast(h16x2, p01);
        h16x2 q23 = __builtin_bit_cast(h16x2, p23);
        h16x2 q45 = __builtin_bit_cast(h16x2, p45);
        h16x2 q67 = __builtin_bit_cast(h16x2, p67);
        h16x4 pl = __builtin_shufflevector(q01, q23, 0, 1, 2, 3);
        h16x4 ph = __builtin_shufflevector(q45, q67, 0, 1, 2, 3);
        h16x8 pa = __builtin_shufflevector(pl, ph, 0, 1, 2, 3, 4, 5, 6, 7);

#pragma unroll
        for (int jd = 0; jd < 4; jd++)
          O[qn][jd] = MFMA32(pa, vb[jd], O[qn][jd]);
      }
    }
  }

#pragma unroll
  for (int qn = 0; qn < 2; qn++) {
    float v = lsum[qn];
    v += __shfl_xor(v, 16, 64);
    v += __shfl_xor(v, 32, 64);
    if (quad == 0)
      Lp[sp * NH * SEQ + h * SEQ + q0 + wave * 32 + qn * 16 + m] = v;
#pragma unroll
    for (int jd = 0; jd < 4; jd++) {
      int col = h * DH + jd * 16 + m;
#pragma unroll
      for (int r = 0; r < 4; r++) {
        int row = q0 + wave * 32 + qn * 16 + quad * 4 + r;
        if (sp == 0) out0[row * HID + col] = O[qn][jd][r];
        else         Op1[row * HID + col] = f2h(O[qn][jd][r]);
      }
    }
  }
}

// ---------------------------------------------------------------------------
// Kernel 4: combine split-KV partials in place: out = (out + Op1) / (L0+L1)
// ---------------------------------------------------------------------------
__global__ __launch_bounds__(256) void reduce_k(
    float* __restrict__ out, const u16* __restrict__ Op1,
    const float* __restrict__ Lp)
{
  int i = blockIdx.x * 256 + threadIdx.x;
  int s  = i / 192;
  int c4 = i - s * 192;
  int h  = c4 >> 4;
  float L = Lp[h * SEQ + s] + Lp[NH * SEQ + h * SEQ + s];
  float inv = __builtin_amdgcn_rcpf(L);
  float4 a = ((const float4*)out)[i];
  ushort4 b = ((const ushort4*)Op1)[i];
  float4 r;
  r.x = (a.x + h2f(b.x)) * inv;
  r.y = (a.y + h2f(b.y)) * inv;
  r.z = (a.z + h2f(b.z)) * inv;
  r.w = (a.w + h2f(b.w)) * inv;
  ((float4*)out)[i] = r;
}

// ---------------------------------------------------------------------------
// Launch. ws layout (bytes) — TOTAL 28,704,768 (R0-proven footprint):
//   Qh [0, 6291456) | Kh [6291456, 12582912) | Vt [12582912, 18874368)
//   xh [18874368, 25165824) | wqh | wkh | wvh [.., 28704768)
//   Op1 (u16) aliases xh; Lp (f32) aliases wqh — both dead after qkv.
// ---------------------------------------------------------------------------
extern "C" void kernel_launch(void* const* d_in, const int* in_sizes, int n_in,
                              void* d_out, int out_size, void* d_ws, size_t ws_size,
                              hipStream_t stream) {
  const float* x  = (const float*)d_in[0];
  const float* Wq = (const float*)d_in[1];
  const float* bq = (const float*)d_in[2];
  const float* Wk = (const float*)d_in[3];
  const float* bk = (const float*)d_in[4];
  const float* Wv = (const float*)d_in[5];
  const float* bv = (const float*)d_in[6];
  float* out = (float*)d_out;

  char* ws = (char*)d_ws;
  u16* Qh  = (u16*)(ws);
  u16* Kh  = (u16*)(ws + 6291456);
  u16* Vt  = (u16*)(ws + 12582912);
  u16* xh  = (u16*)(ws + 18874368);
  u16* wqh = (u16*)(ws + 25165824);
  u16* wkh = (u16*)(ws + 26345472);
  u16* wvh = (u16*)(ws + 27525120);
  u16*   Op1 = (u16*)(ws + 18874368);    // aliases xh (dead after qkv)
  float* Lp  = (float*)(ws + 25165824);  // aliases wqh (dead after qkv)

  cast_all_k<<<4800, 256, 0, stream>>>(x, Wq, Wk, Wv, xh, wqh, wkh, wvh);
  qkv_gemm_k<<<576, 256, 0, stream>>>(xh, wqh, wkh, wvh,
                                      bq, bk, bv, Qh, Kh, Vt);
  attn_k<<<768, 256, 0, stream>>>(Qh, Kh, Vt, out, Op1, Lp);
  reduce_k<<<3072, 256, 0, stream>>>(out, Op1, Lp);
}